// Round 1
// baseline (1704.626 us; speedup 1.0000x reference)
//
#include <hip/hip_runtime.h>

#define H_DIM 256
#define EPS 1e-5f

// ---------------- setup kernels ----------------

__global__ __launch_bounds__(256) void set_ones_kernel(float* __restrict__ p, int n) {
    int i = blockIdx.x * 256 + threadIdx.x;
    if (i < n) p[i] = 1.0f;
}

__global__ __launch_bounds__(256) void deg_accum_kernel(const int* __restrict__ dst,
                                                        const float* __restrict__ w,
                                                        float* __restrict__ deg, int E) {
    int e = blockIdx.x * 256 + threadIdx.x;
    if (e < E) atomicAdd(&deg[dst[e]], w[e]);
}

__global__ __launch_bounds__(256) void dinv_kernel(const float* __restrict__ deg,
                                                   float* __restrict__ dinv, int n) {
    int i = blockIdx.x * 256 + threadIdx.x;
    if (i < n) {
        float d = deg[i];
        dinv[i] = (d > 0.0f) ? rsqrtf(d) : 0.0f;
    }
}

__global__ __launch_bounds__(256) void count_edges_kernel(const int* __restrict__ dst,
                                                          int* __restrict__ cnt, int E) {
    int e = blockIdx.x * 256 + threadIdx.x;
    if (e < E) atomicAdd(&cnt[dst[e]], 1);
}

// exclusive scan over cnt[0..n-1] -> row_ptr[0..n]; single block of 1024
__global__ __launch_bounds__(1024) void scan_kernel(const int* __restrict__ cnt,
                                                    int* __restrict__ row_ptr, int n) {
    __shared__ int tmp[1024];
    __shared__ int s_carry;
    int tid = threadIdx.x;
    if (tid == 0) s_carry = 0;
    __syncthreads();
    for (int base = 0; base < n; base += 1024) {
        int i = base + tid;
        int v = (i < n) ? cnt[i] : 0;
        tmp[tid] = v;
        __syncthreads();
        for (int off = 1; off < 1024; off <<= 1) {
            int t = (tid >= off) ? tmp[tid - off] : 0;
            __syncthreads();
            tmp[tid] += t;
            __syncthreads();
        }
        int carry = s_carry;
        if (i < n) row_ptr[i + 1] = carry + tmp[tid];
        __syncthreads();
        if (tid == 1023) s_carry = carry + tmp[1023];
        __syncthreads();
    }
    if (tid == 0) row_ptr[0] = 0;
}

__global__ __launch_bounds__(256) void scatter_edges_kernel(
    const int* __restrict__ src, const int* __restrict__ dst,
    const float* __restrict__ w, const int* __restrict__ row_ptr,
    int* __restrict__ cnt2, const float* __restrict__ dinv,
    int* __restrict__ col, float* __restrict__ wn, int E) {
    int e = blockIdx.x * 256 + threadIdx.x;
    if (e < E) {
        int d = dst[e], s = src[e];
        int pos = row_ptr[d] + atomicAdd(&cnt2[d], 1);
        col[pos] = s;
        wn[pos] = dinv[s] * w[e] * dinv[d];
    }
}

// ---------------- fp32 tiled GEMM: C[M,Nc] = A[M,K] @ B[K,Nc] ----------------
// BM=BN=64, BK=16, 256 threads, 4x4 per thread. K % 16 == 0, Nc % 64 == 0.

__global__ __launch_bounds__(256) void gemm_tiled(const float* __restrict__ A,
                                                  const float* __restrict__ B,
                                                  float* __restrict__ C,
                                                  int M, int Nc, int K) {
    __shared__ __align__(16) float As[16][64];  // [k][m]
    __shared__ __align__(16) float Bs[16][64];  // [k][n]
    int tid = threadIdx.x;
    int bx = blockIdx.x;      // N tile
    int by = blockIdx.y;      // M tile
    int tx = tid & 15, ty = tid >> 4;
    int row0 = by * 64, col0 = bx * 64;

    int ar = tid >> 2, ak = (tid & 3) * 4;   // A: row ar, k-offset ak (float4)
    int br = tid >> 4, bc = (tid & 15) * 4;  // B: k-row br, col bc (float4)

    float acc[4][4];
#pragma unroll
    for (int i = 0; i < 4; ++i)
#pragma unroll
        for (int j = 0; j < 4; ++j) acc[i][j] = 0.0f;

    for (int k0 = 0; k0 < K; k0 += 16) {
        float4 av;
        if (row0 + ar < M)
            av = *(const float4*)&A[(size_t)(row0 + ar) * K + k0 + ak];
        else
            av = make_float4(0.f, 0.f, 0.f, 0.f);
        float4 bv = *(const float4*)&B[(size_t)(k0 + br) * Nc + col0 + bc];
        As[ak + 0][ar] = av.x;
        As[ak + 1][ar] = av.y;
        As[ak + 2][ar] = av.z;
        As[ak + 3][ar] = av.w;
        *(float4*)&Bs[br][bc] = bv;
        __syncthreads();
#pragma unroll
        for (int kk = 0; kk < 16; ++kk) {
            float4 a = *(const float4*)&As[kk][ty * 4];
            float4 b = *(const float4*)&Bs[kk][tx * 4];
            acc[0][0] += a.x * b.x; acc[0][1] += a.x * b.y; acc[0][2] += a.x * b.z; acc[0][3] += a.x * b.w;
            acc[1][0] += a.y * b.x; acc[1][1] += a.y * b.y; acc[1][2] += a.y * b.z; acc[1][3] += a.y * b.w;
            acc[2][0] += a.z * b.x; acc[2][1] += a.z * b.y; acc[2][2] += a.z * b.z; acc[2][3] += a.z * b.w;
            acc[3][0] += a.w * b.x; acc[3][1] += a.w * b.y; acc[3][2] += a.w * b.z; acc[3][3] += a.w * b.w;
        }
        __syncthreads();
    }
#pragma unroll
    for (int i = 0; i < 4; ++i) {
        int r = row0 + ty * 4 + i;
        if (r < M) {
            float4 o = make_float4(acc[i][0], acc[i][1], acc[i][2], acc[i][3]);
            *(float4*)&C[(size_t)r * Nc + col0 + tx * 4] = o;
        }
    }
}

// ---------------- aggregation (one block = one dst node, 256 threads = features) --------

__global__ __launch_bounds__(256) void aggregate_first(
    const float* __restrict__ xw, const int* __restrict__ row_ptr,
    const int* __restrict__ col, const float* __restrict__ wn,
    const float* __restrict__ dinv, const float* __restrict__ bias,
    float* __restrict__ out, int n) {
    int d = blockIdx.x;
    int h = threadIdx.x;
    __shared__ int s_col[64];
    __shared__ float s_w[64];
    float di = dinv[d];
    float acc = xw[(size_t)d * H_DIM + h] * (di * di);  // self loop
    int start = row_ptr[d], end = row_ptr[d + 1];
    for (int base = start; base < end; base += 64) {
        int m = min(64, end - base);
        __syncthreads();
        if (h < m) { s_col[h] = col[base + h]; s_w[h] = wn[base + h]; }
        __syncthreads();
        int j = 0;
        for (; j + 8 <= m; j += 8) {
#pragma unroll
            for (int u = 0; u < 8; ++u)
                acc += xw[(size_t)s_col[j + u] * H_DIM + h] * s_w[j + u];
        }
        for (; j < m; ++j) acc += xw[(size_t)s_col[j] * H_DIM + h] * s_w[j];
    }
    out[(size_t)d * H_DIM + h] = acc + bias[h];
}

__global__ __launch_bounds__(256) void aggregate_ln(
    const float* __restrict__ xw, const int* __restrict__ row_ptr,
    const int* __restrict__ col, const float* __restrict__ wn,
    const float* __restrict__ dinv, const float* __restrict__ bias,
    const float* __restrict__ g, const float* __restrict__ lb,
    const float* __restrict__ res, float* __restrict__ out, int n) {
    int d = blockIdx.x;
    int h = threadIdx.x;
    __shared__ int s_col[64];
    __shared__ float s_w[64];
    __shared__ float red[256];
    float di = dinv[d];
    float acc = xw[(size_t)d * H_DIM + h] * (di * di);  // self loop
    int start = row_ptr[d], end = row_ptr[d + 1];
    for (int base = start; base < end; base += 64) {
        int m = min(64, end - base);
        __syncthreads();
        if (h < m) { s_col[h] = col[base + h]; s_w[h] = wn[base + h]; }
        __syncthreads();
        int j = 0;
        for (; j + 8 <= m; j += 8) {
#pragma unroll
            for (int u = 0; u < 8; ++u)
                acc += xw[(size_t)s_col[j + u] * H_DIM + h] * s_w[j + u];
        }
        for (; j < m; ++j) acc += xw[(size_t)s_col[j] * H_DIM + h] * s_w[j];
    }
    float v = acc + bias[h];
    // LayerNorm over the 256 features held by this block
    red[h] = v;
    __syncthreads();
    for (int s = 128; s > 0; s >>= 1) {
        if (h < s) red[h] += red[h + s];
        __syncthreads();
    }
    float mu = red[0] * (1.0f / H_DIM);
    __syncthreads();
    float dv = v - mu;
    red[h] = dv * dv;
    __syncthreads();
    for (int s = 128; s > 0; s >>= 1) {
        if (h < s) red[h] += red[h + s];
        __syncthreads();
    }
    float var = red[0] * (1.0f / H_DIM);
    float rs = rsqrtf(var + EPS);
    float y = dv * rs * g[h] + lb[h];
    float o = y + res[(size_t)d * H_DIM + h];
    out[(size_t)d * H_DIM + h] = (o > 0.0f) ? o : 0.0f;
}

// ---------------- head: mean pool folded into colsum + tiny matvec ----------------

__global__ __launch_bounds__(256) void colsum_kernel(const float* __restrict__ x,
                                                     float* __restrict__ sums, int n) {
    int h = threadIdx.x;
    float acc = 0.0f;
    for (int r = blockIdx.x; r < n; r += gridDim.x) acc += x[(size_t)r * H_DIM + h];
    atomicAdd(&sums[h], acc);
}

__global__ __launch_bounds__(64) void final_kernel(const float* __restrict__ sums,
                                                   const float* __restrict__ fcW,
                                                   const float* __restrict__ fcb,
                                                   float* __restrict__ out, float invN) {
    int lane = threadIdx.x;  // 64
    float p0 = 0.0f, p1 = 0.0f;
    for (int hh = lane; hh < H_DIM; hh += 64) {
        float m = sums[hh];
        p0 += m * fcW[hh * 2 + 0];
        p1 += m * fcW[hh * 2 + 1];
    }
    for (int off = 32; off > 0; off >>= 1) {
        p0 += __shfl_down(p0, off);
        p1 += __shfl_down(p1, off);
    }
    if (lane == 0) {
        out[0] = p0 * invN + fcb[0];
        out[1] = p1 * invN + fcb[1];
    }
}

// ---------------- launch ----------------

extern "C" void kernel_launch(void* const* d_in, const int* in_sizes, int n_in,
                              void* d_out, int out_size, void* d_ws, size_t ws_size,
                              hipStream_t stream) {
    const float* node    = (const float*)d_in[0];
    const int*   edges   = (const int*)d_in[1];
    const float* eattr   = (const float*)d_in[2];
    const float* W1      = (const float*)d_in[3];
    const float* b1      = (const float*)d_in[4];
    const float* W_convs = (const float*)d_in[5];
    const float* b_convs = (const float*)d_in[6];
    const float* ln_g    = (const float*)d_in[7];
    const float* ln_b    = (const float*)d_in[8];
    const float* fc_W    = (const float*)d_in[9];
    const float* fc_b    = (const float*)d_in[10];
    float* out = (float*)d_out;

    const int H = in_sizes[4];           // 256
    const int F = in_sizes[3] / H;       // 128
    const int N = in_sizes[0] / F;       // 50000
    const int E = in_sizes[2];           // 1600000
    const int L = in_sizes[6] / H;       // 3

    const int* src = edges;
    const int* dst = edges + E;

    // workspace carve-up (256B aligned slabs)
    char* p = (char*)d_ws;
    auto alloc = [&](size_t bytes) {
        char* r = p;
        p += (bytes + 255) & ~(size_t)255;
        return r;
    };
    int*   cnt     = (int*)alloc((size_t)N * 4);
    int*   cnt2    = (int*)alloc((size_t)N * 4);
    float* colsums = (float*)alloc((size_t)H * 4);
    size_t zero_bytes = (size_t)((char*)colsums - (char*)cnt) + (((size_t)H * 4 + 255) & ~(size_t)255);
    float* deg     = (float*)alloc((size_t)N * 4);
    float* dinv    = (float*)alloc((size_t)N * 4);
    int*   row_ptr = (int*)alloc((size_t)(N + 1) * 4);
    int*   col     = (int*)alloc((size_t)E * 4);
    float* wn      = (float*)alloc((size_t)E * 4);
    float* bufA    = (float*)alloc((size_t)N * H * 4);
    float* bufB    = (float*)alloc((size_t)N * H * 4);
    float* bufXW   = (float*)alloc((size_t)N * H * 4);

    hipMemsetAsync(cnt, 0, zero_bytes, stream);

    int gN = (N + 255) / 256, gE = (E + 255) / 256;
    set_ones_kernel<<<gN, 256, 0, stream>>>(deg, N);
    deg_accum_kernel<<<gE, 256, 0, stream>>>(dst, eattr, deg, E);
    dinv_kernel<<<gN, 256, 0, stream>>>(deg, dinv, N);
    count_edges_kernel<<<gE, 256, 0, stream>>>(dst, cnt, E);
    scan_kernel<<<1, 1024, 0, stream>>>(cnt, row_ptr, N);
    scatter_edges_kernel<<<gE, 256, 0, stream>>>(src, dst, eattr, row_ptr, cnt2, dinv, col, wn, E);

    dim3 ggrid(H / 64, (N + 63) / 64);

    // layer 1: xw = node @ W1 ; x = aggregate(xw) + b1
    gemm_tiled<<<ggrid, 256, 0, stream>>>(node, W1, bufXW, N, H, F);
    aggregate_first<<<N, 256, 0, stream>>>(bufXW, row_ptr, col, wn, dinv, b1, bufA, N);

    float* x = bufA;
    float* other = bufB;
    for (int i = 0; i < L; ++i) {
        gemm_tiled<<<ggrid, 256, 0, stream>>>(x, W_convs + (size_t)i * H * H, bufXW, N, H, H);
        aggregate_ln<<<N, 256, 0, stream>>>(bufXW, row_ptr, col, wn, dinv,
                                            b_convs + (size_t)i * H, ln_g + (size_t)i * H,
                                            ln_b + (size_t)i * H, x, other, N);
        float* t = x; x = other; other = t;
    }

    colsum_kernel<<<256, 256, 0, stream>>>(x, colsums, N);
    final_kernel<<<1, 64, 0, stream>>>(colsums, fc_W, fc_b, out, 1.0f / (float)N);
}

// Round 2
// 1194.170 us; speedup vs baseline: 1.4275x; 1.4275x over previous
//
#include <hip/hip_runtime.h>

#define H_DIM 256
#define EPS 1e-5f

typedef __attribute__((ext_vector_type(8))) short short8;
typedef __attribute__((ext_vector_type(4))) short short4v;
typedef __attribute__((ext_vector_type(4))) float float4v;

__device__ __forceinline__ unsigned short f2b(float f) {
    union { float f; unsigned u; } v; v.f = f;
    unsigned r = v.u + 0x7FFF + ((v.u >> 16) & 1);   // RNE
    return (unsigned short)(r >> 16);
}
__device__ __forceinline__ float b2f(unsigned short u) {
    union { unsigned u; float f; } v; v.u = ((unsigned)u) << 16;
    return v.f;
}

// ---------------- setup kernels ----------------

__global__ __launch_bounds__(256) void set_ones_kernel(float* __restrict__ p, int n) {
    int i = blockIdx.x * 256 + threadIdx.x;
    if (i < n) p[i] = 1.0f;
}

__global__ __launch_bounds__(256) void deg_accum_kernel(const int* __restrict__ dst,
                                                        const float* __restrict__ w,
                                                        float* __restrict__ deg, int E) {
    int e = blockIdx.x * 256 + threadIdx.x;
    if (e < E) atomicAdd(&deg[dst[e]], w[e]);
}

__global__ __launch_bounds__(256) void dinv_kernel(const float* __restrict__ deg,
                                                   float* __restrict__ dinv, int n) {
    int i = blockIdx.x * 256 + threadIdx.x;
    if (i < n) {
        float d = deg[i];
        dinv[i] = (d > 0.0f) ? rsqrtf(d) : 0.0f;
    }
}

__global__ __launch_bounds__(256) void count_edges_kernel(const int* __restrict__ dst,
                                                          int* __restrict__ cnt, int E) {
    int e = blockIdx.x * 256 + threadIdx.x;
    if (e < E) atomicAdd(&cnt[dst[e]], 1);
}

// exclusive scan cnt[0..n-1] -> row_ptr[0..n]; single block 1024, shfl-based
__global__ __launch_bounds__(1024) void scan_kernel(const int* __restrict__ cnt,
                                                    int* __restrict__ row_ptr, int n) {
    __shared__ int wsum[16];
    __shared__ int s_carry;
    int tid = threadIdx.x, lane = tid & 63, w = tid >> 6;
    if (tid == 0) s_carry = 0;
    __syncthreads();
    for (int base = 0; base < n; base += 1024) {
        int i = base + tid;
        int x = (i < n) ? cnt[i] : 0;
        for (int off = 1; off < 64; off <<= 1) {
            int t = __shfl_up(x, off);
            if (lane >= off) x += t;
        }
        if (lane == 63) wsum[w] = x;
        __syncthreads();
        if (w == 0 && lane < 16) {
            int s = wsum[lane];
            for (int off = 1; off < 16; off <<= 1) {
                int t = __shfl_up(s, off, 16);
                if (lane >= off) s += t;
            }
            wsum[lane] = s;
        }
        __syncthreads();
        int carry = s_carry;
        int woff = (w > 0) ? wsum[w - 1] : 0;
        if (i < n) row_ptr[i + 1] = carry + woff + x;
        __syncthreads();
        if (tid == 0) s_carry = carry + wsum[15];
        __syncthreads();
    }
    if (tid == 0) row_ptr[0] = 0;
}

__global__ __launch_bounds__(256) void scatter_edges_kernel(
    const int* __restrict__ src, const int* __restrict__ dst,
    const float* __restrict__ w, const int* __restrict__ row_ptr,
    int* __restrict__ cnt2, const float* __restrict__ dinv,
    int* __restrict__ col, float* __restrict__ wn, int E) {
    int e = blockIdx.x * 256 + threadIdx.x;
    if (e < E) {
        int d = dst[e], s = src[e];
        int pos = row_ptr[d] + atomicAdd(&cnt2[d], 1);
        col[pos] = s;
        wn[pos] = dinv[s] * w[e] * dinv[d];
    }
}

// transpose + f32->bf16: Wt[n*K + k] = bf16(W[k*Nc + n]);  total = K*Nc elems of out
__global__ __launch_bounds__(256) void wtrans_kernel(const float* __restrict__ W,
                                                     unsigned short* __restrict__ Wt,
                                                     int K, int Nc) {
    int o = blockIdx.x * 256 + threadIdx.x;
    if (o < K * Nc) {
        int n = o / K, k = o - n * K;
        Wt[o] = f2b(W[(size_t)k * Nc + n]);
    }
}

// ---------------- bf16 MFMA GEMM: C[M,Nc](bf16) = A[M,K](f32) @ Bt[Nc,K](bf16)^T ----
// block = 256 thr (4 waves), tile 64x64, BK=128 staged in LDS (stride 136 shorts).
// wave w: rows [16w,16w+16), 4 col-tiles of 16.  mfma_f32_16x16x32_bf16.

#define BK 128
#define LDSTRIDE 136   // +8 shorts: 16B-aligned rows, 2-way bank alias (free)

__global__ __launch_bounds__(256) void gemm_mfma(const float* __restrict__ A,
                                                 const unsigned short* __restrict__ Bt,
                                                 unsigned short* __restrict__ C,
                                                 int M, int Nc, int K) {
    __shared__ __align__(16) short As[64 * LDSTRIDE];
    __shared__ __align__(16) short Bs[64 * LDSTRIDE];
    int t = threadIdx.x;
    int lane = t & 63, w = t >> 6;
    int quad = lane >> 4, l16 = lane & 15;
    int row0 = blockIdx.y * 64, col0 = blockIdx.x * 64;

    float4v acc[4];
#pragma unroll
    for (int c = 0; c < 4; ++c) acc[c] = (float4v){0.f, 0.f, 0.f, 0.f};

    for (int k_outer = 0; k_outer < K; k_outer += BK) {
        // stage A: 64 rows x 128 k (f32 -> bf16), 2048 float4s, 8/thread
#pragma unroll
        for (int j = 0; j < 8; ++j) {
            int idx = t + 256 * j;
            int row = idx >> 5, c4 = idx & 31;
            short4v sv;
            if (row0 + row < M) {
                float4 av = *(const float4*)&A[(size_t)(row0 + row) * K + k_outer + c4 * 4];
                sv = (short4v){(short)f2b(av.x), (short)f2b(av.y), (short)f2b(av.z), (short)f2b(av.w)};
            } else {
                sv = (short4v){0, 0, 0, 0};
            }
            *(short4v*)&As[row * LDSTRIDE + c4 * 4] = sv;
        }
        // stage B: 64 cols x 128 k bf16, 1024 uint4s, 4/thread
#pragma unroll
        for (int j = 0; j < 4; ++j) {
            int idx = t + 256 * j;
            int n = idx >> 4, g8 = idx & 15;
            uint4 bv = *(const uint4*)&Bt[(size_t)(col0 + n) * K + k_outer + g8 * 8];
            *(uint4*)&Bs[n * LDSTRIDE + g8 * 8] = bv;
        }
        __syncthreads();
#pragma unroll
        for (int k0 = 0; k0 < BK; k0 += 32) {
            short8 a = *(const short8*)&As[(w * 16 + l16) * LDSTRIDE + k0 + quad * 8];
#pragma unroll
            for (int c = 0; c < 4; ++c) {
                short8 b = *(const short8*)&Bs[(c * 16 + l16) * LDSTRIDE + k0 + quad * 8];
                acc[c] = __builtin_amdgcn_mfma_f32_16x16x32_bf16(a, b, acc[c], 0, 0, 0);
            }
        }
        __syncthreads();
    }
    // epilogue: C[row=quad*4+r][col=l16] per 16x16 tile
#pragma unroll
    for (int c = 0; c < 4; ++c) {
#pragma unroll
        for (int r = 0; r < 4; ++r) {
            int row = row0 + w * 16 + quad * 4 + r;
            if (row < M) C[(size_t)row * Nc + col0 + c * 16 + l16] = f2b(acc[c][r]);
        }
    }
}

// ---------------- aggregation (one block = one dst node, 256 thr = features) --------

__global__ __launch_bounds__(256) void aggregate_first(
    const unsigned short* __restrict__ xw, const int* __restrict__ row_ptr,
    const int* __restrict__ col, const float* __restrict__ wn,
    const float* __restrict__ dinv, const float* __restrict__ bias,
    float* __restrict__ out, int n) {
    int d = blockIdx.x;
    int h = threadIdx.x;
    __shared__ int s_col[64];
    __shared__ float s_w[64];
    float di = dinv[d];
    float acc = b2f(xw[(size_t)d * H_DIM + h]) * (di * di);  // self loop
    int start = row_ptr[d], end = row_ptr[d + 1];
    for (int base = start; base < end; base += 64) {
        int m = min(64, end - base);
        __syncthreads();
        if (h < m) { s_col[h] = col[base + h]; s_w[h] = wn[base + h]; }
        __syncthreads();
        int j = 0;
        for (; j + 8 <= m; j += 8) {
#pragma unroll
            for (int u = 0; u < 8; ++u)
                acc += b2f(xw[(size_t)s_col[j + u] * H_DIM + h]) * s_w[j + u];
        }
        for (; j < m; ++j) acc += b2f(xw[(size_t)s_col[j] * H_DIM + h]) * s_w[j];
    }
    out[(size_t)d * H_DIM + h] = acc + bias[h];
}

__global__ __launch_bounds__(256) void aggregate_ln(
    const unsigned short* __restrict__ xw, const int* __restrict__ row_ptr,
    const int* __restrict__ col, const float* __restrict__ wn,
    const float* __restrict__ dinv, const float* __restrict__ bias,
    const float* __restrict__ g, const float* __restrict__ lb,
    const float* __restrict__ res, float* __restrict__ out, int n) {
    int d = blockIdx.x;
    int h = threadIdx.x;
    __shared__ int s_col[64];
    __shared__ float s_w[64];
    __shared__ float red[256];
    float di = dinv[d];
    float acc = b2f(xw[(size_t)d * H_DIM + h]) * (di * di);  // self loop
    int start = row_ptr[d], end = row_ptr[d + 1];
    for (int base = start; base < end; base += 64) {
        int m = min(64, end - base);
        __syncthreads();
        if (h < m) { s_col[h] = col[base + h]; s_w[h] = wn[base + h]; }
        __syncthreads();
        int j = 0;
        for (; j + 8 <= m; j += 8) {
#pragma unroll
            for (int u = 0; u < 8; ++u)
                acc += b2f(xw[(size_t)s_col[j + u] * H_DIM + h]) * s_w[j + u];
        }
        for (; j < m; ++j) acc += b2f(xw[(size_t)s_col[j] * H_DIM + h]) * s_w[j];
    }
    float v = acc + bias[h];
    // LayerNorm over the 256 features held by this block
    red[h] = v;
    __syncthreads();
    for (int s = 128; s > 0; s >>= 1) {
        if (h < s) red[h] += red[h + s];
        __syncthreads();
    }
    float mu = red[0] * (1.0f / H_DIM);
    __syncthreads();
    float dv = v - mu;
    red[h] = dv * dv;
    __syncthreads();
    for (int s = 128; s > 0; s >>= 1) {
        if (h < s) red[h] += red[h + s];
        __syncthreads();
    }
    float var = red[0] * (1.0f / H_DIM);
    float rs = rsqrtf(var + EPS);
    float y = dv * rs * g[h] + lb[h];
    float o = y + res[(size_t)d * H_DIM + h];
    out[(size_t)d * H_DIM + h] = (o > 0.0f) ? o : 0.0f;
}

// ---------------- head: mean pool folded into colsum + tiny matvec ----------------

__global__ __launch_bounds__(256) void colsum_kernel(const float* __restrict__ x,
                                                     float* __restrict__ sums, int n) {
    int h = threadIdx.x;
    float acc = 0.0f;
    for (int r = blockIdx.x; r < n; r += gridDim.x) acc += x[(size_t)r * H_DIM + h];
    atomicAdd(&sums[h], acc);
}

__global__ __launch_bounds__(64) void final_kernel(const float* __restrict__ sums,
                                                   const float* __restrict__ fcW,
                                                   const float* __restrict__ fcb,
                                                   float* __restrict__ out, float invN) {
    int lane = threadIdx.x;  // 64
    float p0 = 0.0f, p1 = 0.0f;
    for (int hh = lane; hh < H_DIM; hh += 64) {
        float m = sums[hh];
        p0 += m * fcW[hh * 2 + 0];
        p1 += m * fcW[hh * 2 + 1];
    }
    for (int off = 32; off > 0; off >>= 1) {
        p0 += __shfl_down(p0, off);
        p1 += __shfl_down(p1, off);
    }
    if (lane == 0) {
        out[0] = p0 * invN + fcb[0];
        out[1] = p1 * invN + fcb[1];
    }
}

// ---------------- launch ----------------

extern "C" void kernel_launch(void* const* d_in, const int* in_sizes, int n_in,
                              void* d_out, int out_size, void* d_ws, size_t ws_size,
                              hipStream_t stream) {
    const float* node    = (const float*)d_in[0];
    const int*   edges   = (const int*)d_in[1];
    const float* eattr   = (const float*)d_in[2];
    const float* W1      = (const float*)d_in[3];
    const float* b1      = (const float*)d_in[4];
    const float* W_convs = (const float*)d_in[5];
    const float* b_convs = (const float*)d_in[6];
    const float* ln_g    = (const float*)d_in[7];
    const float* ln_b    = (const float*)d_in[8];
    const float* fc_W    = (const float*)d_in[9];
    const float* fc_b    = (const float*)d_in[10];
    float* out = (float*)d_out;

    const int H = in_sizes[4];           // 256
    const int F = in_sizes[3] / H;       // 128
    const int N = in_sizes[0] / F;       // 50000
    const int E = in_sizes[2];           // 1600000
    const int L = in_sizes[6] / H;       // 3

    const int* src = edges;
    const int* dst = edges + E;

    // workspace carve-up (256B aligned slabs)
    char* p = (char*)d_ws;
    auto alloc = [&](size_t bytes) {
        char* r = p;
        p += (bytes + 255) & ~(size_t)255;
        return r;
    };
    int*   cnt     = (int*)alloc((size_t)N * 4);
    int*   cnt2    = (int*)alloc((size_t)N * 4);
    float* colsums = (float*)alloc((size_t)H * 4);
    size_t zero_bytes = (size_t)((char*)colsums - (char*)cnt) + (((size_t)H * 4 + 255) & ~(size_t)255);
    float* deg     = (float*)alloc((size_t)N * 4);
    float* dinv    = (float*)alloc((size_t)N * 4);
    int*   row_ptr = (int*)alloc((size_t)(N + 1) * 4);
    int*   col     = (int*)alloc((size_t)E * 4);
    float* wn      = (float*)alloc((size_t)E * 4);
    unsigned short* Wt1  = (unsigned short*)alloc((size_t)H * F * 2);
    unsigned short* Wtc  = (unsigned short*)alloc((size_t)L * H * H * 2);
    unsigned short* xw   = (unsigned short*)alloc((size_t)N * H * 2);  // bf16 gather table
    float* bufA    = (float*)alloc((size_t)N * H * 4);
    float* bufB    = (float*)alloc((size_t)N * H * 4);

    hipMemsetAsync(cnt, 0, zero_bytes, stream);

    int gN = (N + 255) / 256, gE = (E + 255) / 256;
    set_ones_kernel<<<gN, 256, 0, stream>>>(deg, N);
    deg_accum_kernel<<<gE, 256, 0, stream>>>(dst, eattr, deg, E);
    dinv_kernel<<<gN, 256, 0, stream>>>(deg, dinv, N);
    count_edges_kernel<<<gE, 256, 0, stream>>>(dst, cnt, E);
    scan_kernel<<<1, 1024, 0, stream>>>(cnt, row_ptr, N);
    scatter_edges_kernel<<<gE, 256, 0, stream>>>(src, dst, eattr, row_ptr, cnt2, dinv, col, wn, E);

    // weight prep (bf16, transposed to [Nc][K])
    wtrans_kernel<<<(F * H + 255) / 256, 256, 0, stream>>>(W1, Wt1, F, H);
    for (int i = 0; i < L; ++i)
        wtrans_kernel<<<(H * H + 255) / 256, 256, 0, stream>>>(
            W_convs + (size_t)i * H * H, Wtc + (size_t)i * H * H, H, H);

    dim3 ggrid(H / 64, (N + 63) / 64);

    // layer 1: xw = node @ W1 (bf16 out); x = aggregate(xw) + b1
    gemm_mfma<<<ggrid, 256, 0, stream>>>(node, Wt1, xw, N, H, F);
    aggregate_first<<<N, 256, 0, stream>>>(xw, row_ptr, col, wn, dinv, b1, bufA, N);

    float* x = bufA;
    float* other = bufB;
    for (int i = 0; i < L; ++i) {
        gemm_mfma<<<ggrid, 256, 0, stream>>>(x, Wtc + (size_t)i * H * H, xw, N, H, H);
        aggregate_ln<<<N, 256, 0, stream>>>(xw, row_ptr, col, wn, dinv,
                                            b_convs + (size_t)i * H, ln_g + (size_t)i * H,
                                            ln_b + (size_t)i * H, x, other, N);
        float* t = x; x = other; other = t;
    }

    colsum_kernel<<<256, 256, 0, stream>>>(x, colsums, N);
    final_kernel<<<1, 64, 0, stream>>>(colsums, fc_W, fc_b, out, 1.0f / (float)N);
}

// Round 3
// 1069.343 us; speedup vs baseline: 1.5941x; 1.1167x over previous
//
#include <hip/hip_runtime.h>

#define H_DIM 256
#define EPS 1e-5f

typedef __attribute__((ext_vector_type(8))) short short8;
typedef __attribute__((ext_vector_type(4))) short short4v;
typedef __attribute__((ext_vector_type(4))) float float4v;

__device__ __forceinline__ unsigned short f2b(float f) {
    union { float f; unsigned u; } v; v.f = f;
    unsigned r = v.u + 0x7FFF + ((v.u >> 16) & 1);   // RNE
    return (unsigned short)(r >> 16);
}
__device__ __forceinline__ float b2f(unsigned short u) {
    union { unsigned u; float f; } v; v.u = ((unsigned)u) << 16;
    return v.f;
}

// ---------------- setup kernels ----------------

// one pass over edges: weighted degree + edge count per dst
__global__ __launch_bounds__(256) void deg_count_kernel(const int* __restrict__ dst,
                                                        const float* __restrict__ w,
                                                        float* __restrict__ deg,
                                                        int* __restrict__ cnt, int E) {
    int e = blockIdx.x * 256 + threadIdx.x;
    if (e < E) {
        int d = dst[e];
        atomicAdd(&deg[d], w[e]);
        atomicAdd(&cnt[d], 1);
    }
}

// exclusive scan cnt -> row_ptr[0..n] and cursor[i]=row_ptr[i]; also dinv = rsqrt(1+deg)
__global__ __launch_bounds__(1024) void scan_dinv_kernel(const int* __restrict__ cnt,
                                                         const float* __restrict__ deg,
                                                         int* __restrict__ row_ptr,
                                                         int* __restrict__ cursor,
                                                         float* __restrict__ dinv, int n) {
    int tid = threadIdx.x, lane = tid & 63, w = tid >> 6;
    // dinv (deg = 1 + sum(w) > 0 always)
    for (int i = tid; i < n; i += 1024) dinv[i] = rsqrtf(deg[i] + 1.0f);

    __shared__ int wsum[16];
    __shared__ int s_carry;
    if (tid == 0) s_carry = 0;
    __syncthreads();
    for (int base = 0; base < n; base += 1024) {
        int i = base + tid;
        int v = (i < n) ? cnt[i] : 0;
        int x = v;
        for (int off = 1; off < 64; off <<= 1) {
            int t = __shfl_up(x, off);
            if (lane >= off) x += t;
        }
        if (lane == 63) wsum[w] = x;
        __syncthreads();
        if (w == 0 && lane < 16) {
            int s = wsum[lane];
            for (int off = 1; off < 16; off <<= 1) {
                int t = __shfl_up(s, off, 16);
                if (lane >= off) s += t;
            }
            wsum[lane] = s;
        }
        __syncthreads();
        int carry = s_carry;
        int woff = (w > 0) ? wsum[w - 1] : 0;
        if (i < n) {
            row_ptr[i + 1] = carry + woff + x;
            cursor[i] = carry + woff + x - v;   // exclusive prefix
        }
        __syncthreads();
        if (tid == 0) s_carry = carry + wsum[15];
        __syncthreads();
    }
    if (tid == 0) row_ptr[0] = 0;
}

// build interleaved CSR edge data {src, norm_weight}
__global__ __launch_bounds__(256) void scatter_edges_kernel(
    const int* __restrict__ src, const int* __restrict__ dst,
    const float* __restrict__ w, int* __restrict__ cursor,
    const float* __restrict__ dinv, int2* __restrict__ edge, int E) {
    int e = blockIdx.x * 256 + threadIdx.x;
    if (e < E) {
        int d = dst[e], s = src[e];
        int pos = atomicAdd(&cursor[d], 1);
        float wn = dinv[s] * w[e] * dinv[d];
        edge[pos] = make_int2(s, __float_as_int(wn));
    }
}

// transpose + f32->bf16: Wt[n*K + k] = bf16(W[k*Nc + n])
__global__ __launch_bounds__(256) void wtrans_kernel(const float* __restrict__ W,
                                                     unsigned short* __restrict__ Wt,
                                                     int K, int Nc) {
    int o = blockIdx.x * 256 + threadIdx.x;
    if (o < K * Nc) {
        int n = o / K, k = o - n * K;
        Wt[o] = f2b(W[(size_t)k * Nc + n]);
    }
}

// ---------------- bf16 MFMA GEMM: C[M,Nc](bf16) = A[M,K](f32) @ Bt[Nc,K](bf16)^T ----

#define BK 128
#define LDSTRIDE 136

__global__ __launch_bounds__(256) void gemm_mfma(const float* __restrict__ A,
                                                 const unsigned short* __restrict__ Bt,
                                                 unsigned short* __restrict__ C,
                                                 int M, int Nc, int K) {
    __shared__ __align__(16) short As[64 * LDSTRIDE];
    __shared__ __align__(16) short Bs[64 * LDSTRIDE];
    int t = threadIdx.x;
    int lane = t & 63, w = t >> 6;
    int quad = lane >> 4, l16 = lane & 15;
    int row0 = blockIdx.y * 64, col0 = blockIdx.x * 64;

    float4v acc[4];
#pragma unroll
    for (int c = 0; c < 4; ++c) acc[c] = (float4v){0.f, 0.f, 0.f, 0.f};

    for (int k_outer = 0; k_outer < K; k_outer += BK) {
#pragma unroll
        for (int j = 0; j < 8; ++j) {
            int idx = t + 256 * j;
            int row = idx >> 5, c4 = idx & 31;
            short4v sv;
            if (row0 + row < M) {
                float4 av = *(const float4*)&A[(size_t)(row0 + row) * K + k_outer + c4 * 4];
                sv = (short4v){(short)f2b(av.x), (short)f2b(av.y), (short)f2b(av.z), (short)f2b(av.w)};
            } else {
                sv = (short4v){0, 0, 0, 0};
            }
            *(short4v*)&As[row * LDSTRIDE + c4 * 4] = sv;
        }
#pragma unroll
        for (int j = 0; j < 4; ++j) {
            int idx = t + 256 * j;
            int n = idx >> 4, g8 = idx & 15;
            uint4 bv = *(const uint4*)&Bt[(size_t)(col0 + n) * K + k_outer + g8 * 8];
            *(uint4*)&Bs[n * LDSTRIDE + g8 * 8] = bv;
        }
        __syncthreads();
#pragma unroll
        for (int k0 = 0; k0 < BK; k0 += 32) {
            short8 a = *(const short8*)&As[(w * 16 + l16) * LDSTRIDE + k0 + quad * 8];
#pragma unroll
            for (int c = 0; c < 4; ++c) {
                short8 b = *(const short8*)&Bs[(c * 16 + l16) * LDSTRIDE + k0 + quad * 8];
                acc[c] = __builtin_amdgcn_mfma_f32_16x16x32_bf16(a, b, acc[c], 0, 0, 0);
            }
        }
        __syncthreads();
    }
#pragma unroll
    for (int c = 0; c < 4; ++c) {
#pragma unroll
        for (int r = 0; r < 4; ++r) {
            int row = row0 + w * 16 + quad * 4 + r;
            if (row < M) C[(size_t)row * Nc + col0 + c * 16 + l16] = f2b(acc[c][r]);
        }
    }
}

// ---------------- aggregation: one WAVE per dst node, lane l owns features 4l..4l+3 ----

__device__ __forceinline__ void gather_fma(const unsigned short* __restrict__ xw,
                                           int s, float wgt, int l, float* a) {
    ushort4 r = *(const ushort4*)&xw[(size_t)s * H_DIM + 4 * l];
    a[0] += b2f(r.x) * wgt;
    a[1] += b2f(r.y) * wgt;
    a[2] += b2f(r.z) * wgt;
    a[3] += b2f(r.w) * wgt;
}

__global__ __launch_bounds__(256) void aggregate_first(
    const unsigned short* __restrict__ xw, const int* __restrict__ row_ptr,
    const int2* __restrict__ edge, const float* __restrict__ dinv,
    const float* __restrict__ bias, float* __restrict__ out, int n) {
    int wv = __builtin_amdgcn_readfirstlane(threadIdx.x >> 6);
    int d = blockIdx.x * 4 + wv;
    if (d >= n) return;
    int l = threadIdx.x & 63;
    float di = dinv[d];
    float selfw = di * di;
    float a[4] = {0.f, 0.f, 0.f, 0.f};
    gather_fma(xw, d, selfw, l, a);
    int j = row_ptr[d], r1 = row_ptr[d + 1];
    for (; j + 4 <= r1; j += 4) {
        int2 e0 = edge[j], e1 = edge[j + 1], e2 = edge[j + 2], e3 = edge[j + 3];
        gather_fma(xw, e0.x, __int_as_float(e0.y), l, a);
        gather_fma(xw, e1.x, __int_as_float(e1.y), l, a);
        gather_fma(xw, e2.x, __int_as_float(e2.y), l, a);
        gather_fma(xw, e3.x, __int_as_float(e3.y), l, a);
    }
    for (; j < r1; ++j) {
        int2 e = edge[j];
        gather_fma(xw, e.x, __int_as_float(e.y), l, a);
    }
    float4 bb = *(const float4*)&bias[4 * l];
    float4 o = make_float4(a[0] + bb.x, a[1] + bb.y, a[2] + bb.z, a[3] + bb.w);
    *(float4*)&out[(size_t)d * H_DIM + 4 * l] = o;
}

__global__ __launch_bounds__(256) void aggregate_ln(
    const unsigned short* __restrict__ xw, const int* __restrict__ row_ptr,
    const int2* __restrict__ edge, const float* __restrict__ dinv,
    const float* __restrict__ bias, const float* __restrict__ g,
    const float* __restrict__ lb, const float* __restrict__ res,
    float* __restrict__ out, int n) {
    int wv = __builtin_amdgcn_readfirstlane(threadIdx.x >> 6);
    int d = blockIdx.x * 4 + wv;
    if (d >= n) return;
    int l = threadIdx.x & 63;
    float di = dinv[d];
    float selfw = di * di;
    float a[4] = {0.f, 0.f, 0.f, 0.f};
    gather_fma(xw, d, selfw, l, a);
    int j = row_ptr[d], r1 = row_ptr[d + 1];
    for (; j + 4 <= r1; j += 4) {
        int2 e0 = edge[j], e1 = edge[j + 1], e2 = edge[j + 2], e3 = edge[j + 3];
        gather_fma(xw, e0.x, __int_as_float(e0.y), l, a);
        gather_fma(xw, e1.x, __int_as_float(e1.y), l, a);
        gather_fma(xw, e2.x, __int_as_float(e2.y), l, a);
        gather_fma(xw, e3.x, __int_as_float(e3.y), l, a);
    }
    for (; j < r1; ++j) {
        int2 e = edge[j];
        gather_fma(xw, e.x, __int_as_float(e.y), l, a);
    }
    float4 bb = *(const float4*)&bias[4 * l];
    float v0 = a[0] + bb.x, v1 = a[1] + bb.y, v2 = a[2] + bb.z, v3 = a[3] + bb.w;

    // LayerNorm over 256 features spread across the wave (4 per lane)
    float s = v0 + v1 + v2 + v3;
#pragma unroll
    for (int off = 32; off > 0; off >>= 1) s += __shfl_xor(s, off);
    float mu = s * (1.0f / H_DIM);
    float d0 = v0 - mu, d1 = v1 - mu, d2 = v2 - mu, d3 = v3 - mu;
    float q = d0 * d0 + d1 * d1 + d2 * d2 + d3 * d3;
#pragma unroll
    for (int off = 32; off > 0; off >>= 1) q += __shfl_xor(q, off);
    float rs = rsqrtf(q * (1.0f / H_DIM) + EPS);

    float4 gg = *(const float4*)&g[4 * l];
    float4 lbv = *(const float4*)&lb[4 * l];
    float4 rr = *(const float4*)&res[(size_t)d * H_DIM + 4 * l];
    float o0 = d0 * rs * gg.x + lbv.x + rr.x;
    float o1 = d1 * rs * gg.y + lbv.y + rr.y;
    float o2 = d2 * rs * gg.z + lbv.z + rr.z;
    float o3 = d3 * rs * gg.w + lbv.w + rr.w;
    float4 o = make_float4(o0 > 0.f ? o0 : 0.f, o1 > 0.f ? o1 : 0.f,
                           o2 > 0.f ? o2 : 0.f, o3 > 0.f ? o3 : 0.f);
    *(float4*)&out[(size_t)d * H_DIM + 4 * l] = o;
}

// ---------------- head ----------------

__global__ __launch_bounds__(256) void colsum_kernel(const float* __restrict__ x,
                                                     float* __restrict__ sums, int n) {
    int h = threadIdx.x;
    float acc = 0.0f;
    for (int r = blockIdx.x; r < n; r += gridDim.x) acc += x[(size_t)r * H_DIM + h];
    atomicAdd(&sums[h], acc);
}

__global__ __launch_bounds__(64) void final_kernel(const float* __restrict__ sums,
                                                   const float* __restrict__ fcW,
                                                   const float* __restrict__ fcb,
                                                   float* __restrict__ out, float invN) {
    int lane = threadIdx.x;
    float p0 = 0.0f, p1 = 0.0f;
    for (int hh = lane; hh < H_DIM; hh += 64) {
        float m = sums[hh];
        p0 += m * fcW[hh * 2 + 0];
        p1 += m * fcW[hh * 2 + 1];
    }
    for (int off = 32; off > 0; off >>= 1) {
        p0 += __shfl_down(p0, off);
        p1 += __shfl_down(p1, off);
    }
    if (lane == 0) {
        out[0] = p0 * invN + fcb[0];
        out[1] = p1 * invN + fcb[1];
    }
}

// ---------------- launch ----------------

extern "C" void kernel_launch(void* const* d_in, const int* in_sizes, int n_in,
                              void* d_out, int out_size, void* d_ws, size_t ws_size,
                              hipStream_t stream) {
    const float* node    = (const float*)d_in[0];
    const int*   edges   = (const int*)d_in[1];
    const float* eattr   = (const float*)d_in[2];
    const float* W1      = (const float*)d_in[3];
    const float* b1      = (const float*)d_in[4];
    const float* W_convs = (const float*)d_in[5];
    const float* b_convs = (const float*)d_in[6];
    const float* ln_g    = (const float*)d_in[7];
    const float* ln_b    = (const float*)d_in[8];
    const float* fc_W    = (const float*)d_in[9];
    const float* fc_b    = (const float*)d_in[10];
    float* out = (float*)d_out;

    const int H = in_sizes[4];           // 256
    const int F = in_sizes[3] / H;       // 128
    const int N = in_sizes[0] / F;       // 50000
    const int E = in_sizes[2];           // 1600000
    const int L = in_sizes[6] / H;       // 3

    const int* src = edges;
    const int* dst = edges + E;

    char* p = (char*)d_ws;
    auto alloc = [&](size_t bytes) {
        char* r = p;
        p += (bytes + 255) & ~(size_t)255;
        return r;
    };
    // zeroed region: cnt, deg, colsums (contiguous)
    int*   cnt     = (int*)alloc((size_t)N * 4);
    float* deg     = (float*)alloc((size_t)N * 4);
    float* colsums = (float*)alloc((size_t)H * 4);
    size_t zero_bytes = (size_t)((char*)colsums - (char*)cnt) + (((size_t)H * 4 + 255) & ~(size_t)255);
    int*   cursor  = (int*)alloc((size_t)N * 4);
    float* dinv    = (float*)alloc((size_t)N * 4);
    int*   row_ptr = (int*)alloc((size_t)(N + 1) * 4);
    int2*  edge    = (int2*)alloc((size_t)E * 8);
    unsigned short* Wt1 = (unsigned short*)alloc((size_t)H * F * 2);
    unsigned short* Wtc = (unsigned short*)alloc((size_t)L * H * H * 2);
    unsigned short* xw  = (unsigned short*)alloc((size_t)N * H * 2);
    float* bufA    = (float*)alloc((size_t)N * H * 4);
    float* bufB    = (float*)alloc((size_t)N * H * 4);

    hipMemsetAsync(cnt, 0, zero_bytes, stream);

    int gE = (E + 255) / 256;
    deg_count_kernel<<<gE, 256, 0, stream>>>(dst, eattr, deg, cnt, E);
    scan_dinv_kernel<<<1, 1024, 0, stream>>>(cnt, deg, row_ptr, cursor, dinv, N);
    scatter_edges_kernel<<<gE, 256, 0, stream>>>(src, dst, eattr, cursor, dinv, edge, E);

    wtrans_kernel<<<(F * H + 255) / 256, 256, 0, stream>>>(W1, Wt1, F, H);
    for (int i = 0; i < L; ++i)
        wtrans_kernel<<<(H * H + 255) / 256, 256, 0, stream>>>(
            W_convs + (size_t)i * H * H, Wtc + (size_t)i * H * H, H, H);

    dim3 ggrid(H / 64, (N + 63) / 64);
    int agg_grid = (N + 3) / 4;

    gemm_mfma<<<ggrid, 256, 0, stream>>>(node, Wt1, xw, N, H, F);
    aggregate_first<<<agg_grid, 256, 0, stream>>>(xw, row_ptr, edge, dinv, b1, bufA, N);

    float* x = bufA;
    float* other = bufB;
    for (int i = 0; i < L; ++i) {
        gemm_mfma<<<ggrid, 256, 0, stream>>>(x, Wtc + (size_t)i * H * H, xw, N, H, H);
        aggregate_ln<<<agg_grid, 256, 0, stream>>>(xw, row_ptr, edge, dinv,
                                                   b_convs + (size_t)i * H, ln_g + (size_t)i * H,
                                                   ln_b + (size_t)i * H, x, other, N);
        float* t = x; x = other; other = t;
    }

    colsum_kernel<<<256, 256, 0, stream>>>(x, colsums, N);
    final_kernel<<<1, 64, 0, stream>>>(colsums, fc_W, fc_b, out, 1.0f / (float)N);
}

// Round 4
// 906.527 us; speedup vs baseline: 1.8804x; 1.1796x over previous
//
#include <hip/hip_runtime.h>

#define EPS 1e-5f
#define FIXSCALE 8388608.0f   // 2^23 fixed-point for degree accumulation

typedef __attribute__((ext_vector_type(8))) short short8;
typedef __attribute__((ext_vector_type(4))) short short4v;
typedef __attribute__((ext_vector_type(4))) float float4v;
typedef __attribute__((ext_vector_type(8))) unsigned short ushort8;

__device__ __forceinline__ unsigned short f2b(float f) {
    union { float f; unsigned u; } v; v.f = f;
    unsigned r = v.u + 0x7FFF + ((v.u >> 16) & 1);   // RNE
    return (unsigned short)(r >> 16);
}
__device__ __forceinline__ float b2f(unsigned short u) {
    union { unsigned u; float f; } v; v.u = ((unsigned)u) << 16;
    return v.f;
}

// ---------------- setup kernels ----------------

// f32 -> bf16 cast (node features), vec4
__global__ __launch_bounds__(256) void cast_bf16_kernel(const float* __restrict__ in,
                                                        unsigned short* __restrict__ out,
                                                        int n4) {
    int i = blockIdx.x * 256 + threadIdx.x;
    if (i < n4) {
        float4 v = *(const float4*)&in[i * 4];
        short4v s = (short4v){(short)f2b(v.x), (short)f2b(v.y), (short)f2b(v.z), (short)f2b(v.w)};
        *(short4v*)&out[i * 4] = s;
    }
}

// ONE atomic per edge: combo[d] += (1<<32) | fix(w); returned old>>32 = edge's rank in row d
__global__ __launch_bounds__(256) void rank_kernel(const int* __restrict__ dst,
                                                   const float* __restrict__ w,
                                                   unsigned long long* __restrict__ combo,
                                                   int* __restrict__ rank, int E) {
    int e = blockIdx.x * 256 + threadIdx.x;
    if (e < E) {
        int d = dst[e];
        unsigned long long pack = (1ULL << 32) | (unsigned long long)(unsigned)(w[e] * FIXSCALE);
        unsigned long long old = atomicAdd(&combo[d], pack);
        rank[e] = (int)(old >> 32);
    }
}

// combo -> cnt scan (row_ptr), deg -> dinv
__global__ __launch_bounds__(1024) void scan_dinv_kernel(const unsigned long long* __restrict__ combo,
                                                         int* __restrict__ row_ptr,
                                                         float* __restrict__ dinv, int n) {
    int tid = threadIdx.x, lane = tid & 63, w = tid >> 6;
    __shared__ int wsum[16];
    __shared__ int s_carry;
    if (tid == 0) s_carry = 0;
    __syncthreads();
    for (int base = 0; base < n; base += 1024) {
        int i = base + tid;
        int v = 0;
        if (i < n) {
            unsigned long long cb = combo[i];
            v = (int)(cb >> 32);
            float degv = (float)(unsigned)(cb & 0xffffffffULL) * (1.0f / FIXSCALE);
            dinv[i] = rsqrtf(degv + 1.0f);
        }
        int x = v;
        for (int off = 1; off < 64; off <<= 1) {
            int t = __shfl_up(x, off);
            if (lane >= off) x += t;
        }
        if (lane == 63) wsum[w] = x;
        __syncthreads();
        if (w == 0 && lane < 16) {
            int s = wsum[lane];
            for (int off = 1; off < 16; off <<= 1) {
                int t = __shfl_up(s, off, 16);
                if (lane >= off) s += t;
            }
            wsum[lane] = s;
        }
        __syncthreads();
        int carry = s_carry;
        int woff = (w > 0) ? wsum[w - 1] : 0;
        if (i < n) row_ptr[i + 1] = carry + woff + x;
        __syncthreads();
        if (tid == 0) s_carry = carry + wsum[15];
        __syncthreads();
    }
    if (tid == 0) row_ptr[0] = 0;
}

// atomic-free scatter using precomputed rank
__global__ __launch_bounds__(256) void scatter2_kernel(
    const int* __restrict__ src, const int* __restrict__ dst,
    const float* __restrict__ w, const int* __restrict__ rank,
    const int* __restrict__ row_ptr, const float* __restrict__ dinv,
    int2* __restrict__ edge, int E) {
    int e = blockIdx.x * 256 + threadIdx.x;
    if (e < E) {
        int d = dst[e], s = src[e];
        float wn = dinv[s] * w[e] * dinv[d];
        edge[row_ptr[d] + rank[e]] = make_int2(s, __float_as_int(wn));
    }
}

// transpose + f32->bf16: Wt[n*K + k] = bf16(W[k*Nc + n])
__global__ __launch_bounds__(256) void wtrans_kernel(const float* __restrict__ W,
                                                     unsigned short* __restrict__ Wt,
                                                     int K, int Nc) {
    int o = blockIdx.x * 256 + threadIdx.x;
    if (o < K * Nc) {
        int n = o / K, k = o - n * K;
        Wt[o] = f2b(W[(size_t)k * Nc + n]);
    }
}

// ---------------- bf16 MFMA GEMM: C[M,Nc] = A[M,K](f32) @ Bt[Nc,K](bf16)^T ----
// F32OUT: write f32 + bias[col] (layer 1).  else: write bf16 (xw table).

#define BK 128
#define LDSTRIDE 136

template <bool F32OUT>
__global__ __launch_bounds__(256) void gemm_mfma(const float* __restrict__ A,
                                                 const unsigned short* __restrict__ Bt,
                                                 void* __restrict__ Cout,
                                                 const float* __restrict__ bias,
                                                 int M, int Nc, int K) {
    __shared__ __align__(16) short As[64 * LDSTRIDE];
    __shared__ __align__(16) short Bs[64 * LDSTRIDE];
    int t = threadIdx.x;
    int lane = t & 63, w = t >> 6;
    int quad = lane >> 4, l16 = lane & 15;
    int row0 = blockIdx.y * 64, col0 = blockIdx.x * 64;

    float4v acc[4];
#pragma unroll
    for (int c = 0; c < 4; ++c) acc[c] = (float4v){0.f, 0.f, 0.f, 0.f};

    for (int k_outer = 0; k_outer < K; k_outer += BK) {
#pragma unroll
        for (int j = 0; j < 8; ++j) {
            int idx = t + 256 * j;
            int row = idx >> 5, c4 = idx & 31;
            short4v sv;
            if (row0 + row < M) {
                float4 av = *(const float4*)&A[(size_t)(row0 + row) * K + k_outer + c4 * 4];
                sv = (short4v){(short)f2b(av.x), (short)f2b(av.y), (short)f2b(av.z), (short)f2b(av.w)};
            } else {
                sv = (short4v){0, 0, 0, 0};
            }
            *(short4v*)&As[row * LDSTRIDE + c4 * 4] = sv;
        }
#pragma unroll
        for (int j = 0; j < 4; ++j) {
            int idx = t + 256 * j;
            int n = idx >> 4, g8 = idx & 15;
            uint4 bv = *(const uint4*)&Bt[(size_t)(col0 + n) * K + k_outer + g8 * 8];
            *(uint4*)&Bs[n * LDSTRIDE + g8 * 8] = bv;
        }
        __syncthreads();
#pragma unroll
        for (int k0 = 0; k0 < BK; k0 += 32) {
            short8 a = *(const short8*)&As[(w * 16 + l16) * LDSTRIDE + k0 + quad * 8];
#pragma unroll
            for (int c = 0; c < 4; ++c) {
                short8 b = *(const short8*)&Bs[(c * 16 + l16) * LDSTRIDE + k0 + quad * 8];
                acc[c] = __builtin_amdgcn_mfma_f32_16x16x32_bf16(a, b, acc[c], 0, 0, 0);
            }
        }
        __syncthreads();
    }
#pragma unroll
    for (int c = 0; c < 4; ++c) {
        int col = col0 + c * 16 + l16;
        float bcol = F32OUT ? bias[col] : 0.0f;
#pragma unroll
        for (int r = 0; r < 4; ++r) {
            int row = row0 + w * 16 + quad * 4 + r;
            if (row < M) {
                if (F32OUT)
                    ((float*)Cout)[(size_t)row * Nc + col] = acc[c][r] + bcol;
                else
                    ((unsigned short*)Cout)[(size_t)row * Nc + col] = f2b(acc[c][r]);
            }
        }
    }
}

// ---------------- layer-1 aggregation on raw node features (F=128, bf16 rows of 256B) ----
// one wave per node; 4 edges per vmem instr: quarter q covers one edge's row (16 lanes x 16B)

__global__ __launch_bounds__(256) void agg_node(
    const unsigned short* __restrict__ nodeb, const int* __restrict__ row_ptr,
    const int2* __restrict__ edge, const float* __restrict__ dinv,
    float* __restrict__ out, int n) {
    int wv = __builtin_amdgcn_readfirstlane(threadIdx.x >> 6);
    int d = blockIdx.x * 4 + wv;
    if (d >= n) return;
    int l = threadIdx.x & 63;
    int q = l >> 4, sl = l & 15;           // features 8*sl .. 8*sl+7
    int j0 = row_ptr[d];
    int cnt = row_ptr[d + 1] - j0;
    float di = dinv[d];
    float selfw = di * di;

    float a[8] = {0.f, 0.f, 0.f, 0.f, 0.f, 0.f, 0.f, 0.f};
    // peel: q=0 -> self, q=1..3 -> edges 0..2
    {
        bool ev = (q >= 1) && (q - 1 < cnt);
        int2 e = edge[j0 + (ev ? q - 1 : 0)];
        int s = (q == 0) ? d : (ev ? e.x : d);
        float wgt = (q == 0) ? selfw : (ev ? __int_as_float(e.y) : 0.0f);
        ushort8 r = *(const ushort8*)&nodeb[((size_t)s << 7) + (sl << 3)];
#pragma unroll
        for (int k = 0; k < 8; ++k) a[k] += b2f(r[k]) * wgt;
    }
    for (int t = 3; t < cnt; t += 4) {
        int m = t + q;
        bool v = m < cnt;
        int2 e = edge[j0 + (v ? m : 0)];
        int s = v ? e.x : d;
        float wgt = v ? __int_as_float(e.y) : 0.0f;
        ushort8 r = *(const ushort8*)&nodeb[((size_t)s << 7) + (sl << 3)];
#pragma unroll
        for (int k = 0; k < 8; ++k) a[k] += b2f(r[k]) * wgt;
    }
    // combine the 4 quarters
#pragma unroll
    for (int k = 0; k < 8; ++k) {
        a[k] += __shfl_xor(a[k], 16);
        a[k] += __shfl_xor(a[k], 32);
    }
    if (q < 2) {
        float4 o = (q == 0) ? make_float4(a[0], a[1], a[2], a[3])
                            : make_float4(a[4], a[5], a[6], a[7]);
        *(float4*)&out[(size_t)d * 128 + (sl << 3) + q * 4] = o;
    }
}

// ---------------- conv aggregation + bias + LN + residual + ReLU ----------------
// one wave per node; 2 edges per vmem instr: half h covers one edge's 512B row (32 lanes x 16B)

__global__ __launch_bounds__(256) void aggregate_ln2(
    const unsigned short* __restrict__ xw, const int* __restrict__ row_ptr,
    const int2* __restrict__ edge, const float* __restrict__ dinv,
    const float* __restrict__ bias, const float* __restrict__ g,
    const float* __restrict__ lb, const float* __restrict__ res,
    float* __restrict__ out, int n) {
    int wv = __builtin_amdgcn_readfirstlane(threadIdx.x >> 6);
    int d = blockIdx.x * 4 + wv;
    if (d >= n) return;
    int l = threadIdx.x & 63;
    int h = l >> 5, sl = l & 31;           // features 8*sl .. 8*sl+7
    int j0 = row_ptr[d];
    int cnt = row_ptr[d + 1] - j0;
    float di = dinv[d];
    float selfw = di * di;

    float a[8] = {0.f, 0.f, 0.f, 0.f, 0.f, 0.f, 0.f, 0.f};
    // peel: h=0 -> self, h=1 -> edge 0
    {
        bool ev = (h == 1) && (cnt > 0);
        int2 e = edge[j0];
        int s = (h == 0) ? d : (ev ? e.x : d);
        float wgt = (h == 0) ? selfw : (ev ? __int_as_float(e.y) : 0.0f);
        ushort8 r = *(const ushort8*)&xw[((size_t)s << 8) + (sl << 3)];
#pragma unroll
        for (int k = 0; k < 8; ++k) a[k] += b2f(r[k]) * wgt;
    }
    for (int t = 1; t < cnt; t += 4) {
        {
            int m = t + h;
            bool v = m < cnt;
            int2 e = edge[j0 + (v ? m : 0)];
            int s = v ? e.x : d;
            float wgt = v ? __int_as_float(e.y) : 0.0f;
            ushort8 r = *(const ushort8*)&xw[((size_t)s << 8) + (sl << 3)];
#pragma unroll
            for (int k = 0; k < 8; ++k) a[k] += b2f(r[k]) * wgt;
        }
        {
            int m = t + 2 + h;
            bool v = m < cnt;
            int2 e = edge[j0 + (v ? m : 0)];
            int s = v ? e.x : d;
            float wgt = v ? __int_as_float(e.y) : 0.0f;
            ushort8 r = *(const ushort8*)&xw[((size_t)s << 8) + (sl << 3)];
#pragma unroll
            for (int k = 0; k < 8; ++k) a[k] += b2f(r[k]) * wgt;
        }
    }
    // cross-half combine: lane ends with v[j] = total[4h+j], features f = 8*sl + 4*h + j
    int fo = (sl << 3) + (h << 2);
    float4 bb = *(const float4*)&bias[fo];
    float bbv[4] = {bb.x, bb.y, bb.z, bb.w};
    float v[4];
#pragma unroll
    for (int j = 0; j < 4; ++j) {
        float send = h ? a[j] : a[4 + j];
        float keep = h ? a[4 + j] : a[j];
        v[j] = keep + __shfl_xor(send, 32) + bbv[j];
    }
    // LayerNorm over 256 features (4 per lane)
    float s4 = v[0] + v[1] + v[2] + v[3];
#pragma unroll
    for (int off = 1; off < 64; off <<= 1) s4 += __shfl_xor(s4, off);
    float mu = s4 * (1.0f / 256.0f);
    float dv[4];
    float qs = 0.f;
#pragma unroll
    for (int j = 0; j < 4; ++j) { dv[j] = v[j] - mu; qs += dv[j] * dv[j]; }
#pragma unroll
    for (int off = 1; off < 64; off <<= 1) qs += __shfl_xor(qs, off);
    float rs = rsqrtf(qs * (1.0f / 256.0f) + EPS);

    float4 gg = *(const float4*)&g[fo];
    float4 lbv = *(const float4*)&lb[fo];
    float4 rr = *(const float4*)&res[(size_t)d * 256 + fo];
    float ggv[4] = {gg.x, gg.y, gg.z, gg.w};
    float lbvv[4] = {lbv.x, lbv.y, lbv.z, lbv.w};
    float rrv[4] = {rr.x, rr.y, rr.z, rr.w};
    float o[4];
#pragma unroll
    for (int j = 0; j < 4; ++j) {
        float x = dv[j] * rs * ggv[j] + lbvv[j] + rrv[j];
        o[j] = x > 0.f ? x : 0.f;
    }
    *(float4*)&out[(size_t)d * 256 + fo] = make_float4(o[0], o[1], o[2], o[3]);
}

// ---------------- head ----------------

__global__ __launch_bounds__(256) void colsum_kernel(const float* __restrict__ x,
                                                     float* __restrict__ sums, int n) {
    int h = threadIdx.x;
    float acc = 0.0f;
    for (int r = blockIdx.x; r < n; r += gridDim.x) acc += x[(size_t)r * 256 + h];
    atomicAdd(&sums[h], acc);
}

__global__ __launch_bounds__(64) void final_kernel(const float* __restrict__ sums,
                                                   const float* __restrict__ fcW,
                                                   const float* __restrict__ fcb,
                                                   float* __restrict__ out, float invN) {
    int lane = threadIdx.x;
    float p0 = 0.0f, p1 = 0.0f;
    for (int hh = lane; hh < 256; hh += 64) {
        float m = sums[hh];
        p0 += m * fcW[hh * 2 + 0];
        p1 += m * fcW[hh * 2 + 1];
    }
    for (int off = 32; off > 0; off >>= 1) {
        p0 += __shfl_down(p0, off);
        p1 += __shfl_down(p1, off);
    }
    if (lane == 0) {
        out[0] = p0 * invN + fcb[0];
        out[1] = p1 * invN + fcb[1];
    }
}

// ---------------- launch ----------------

extern "C" void kernel_launch(void* const* d_in, const int* in_sizes, int n_in,
                              void* d_out, int out_size, void* d_ws, size_t ws_size,
                              hipStream_t stream) {
    const float* node    = (const float*)d_in[0];
    const int*   edges   = (const int*)d_in[1];
    const float* eattr   = (const float*)d_in[2];
    const float* W1      = (const float*)d_in[3];
    const float* b1      = (const float*)d_in[4];
    const float* W_convs = (const float*)d_in[5];
    const float* b_convs = (const float*)d_in[6];
    const float* ln_g    = (const float*)d_in[7];
    const float* ln_b    = (const float*)d_in[8];
    const float* fc_W    = (const float*)d_in[9];
    const float* fc_b    = (const float*)d_in[10];
    float* out = (float*)d_out;

    const int H = in_sizes[4];           // 256
    const int F = in_sizes[3] / H;       // 128
    const int N = in_sizes[0] / F;       // 50000
    const int E = in_sizes[2];           // 1600000
    const int L = in_sizes[6] / H;       // 3

    const int* src = edges;
    const int* dst = edges + E;

    char* p = (char*)d_ws;
    auto alloc = [&](size_t bytes) {
        char* r = p;
        p += (bytes + 255) & ~(size_t)255;
        return r;
    };
    // zeroed region: combo (u64) + colsums, contiguous
    unsigned long long* combo = (unsigned long long*)alloc((size_t)N * 8);
    float* colsums = (float*)alloc((size_t)H * 4);
    size_t zero_bytes = (size_t)((char*)colsums - (char*)combo) + (((size_t)H * 4 + 255) & ~(size_t)255);
    float* dinv    = (float*)alloc((size_t)N * 4);
    int*   row_ptr = (int*)alloc((size_t)(N + 1) * 4);
    int2*  edge    = (int2*)alloc((size_t)(E + 4) * 8);
    unsigned short* Wt1 = (unsigned short*)alloc((size_t)H * F * 2);
    unsigned short* Wtc = (unsigned short*)alloc((size_t)L * H * H * 2);
    unsigned short* xw  = (unsigned short*)alloc((size_t)N * H * 2);
    float* bufA    = (float*)alloc((size_t)N * H * 4);
    float* bufB    = (float*)alloc((size_t)N * H * 4);
    // transient slabs aliased into bufB (all dead before bufB's first write):
    int*            rank  = (int*)bufB;                                   // N*4 -> E*4? no: E*4
    unsigned short* nodeb = (unsigned short*)((char*)bufB + ((size_t)E * 4 + 255 & ~(size_t)255));
    float*          tmpAgg = (float*)((char*)nodeb + ((size_t)N * F * 2 + 255 & ~(size_t)255));
    // sizes: E*4 (6.4MB) + N*F*2 (12.8MB) + N*F*4 (25.6MB) = 44.8MB <= bufB (51.2MB)

    hipMemsetAsync(combo, 0, zero_bytes, stream);

    int gE = (E + 255) / 256;
    rank_kernel<<<gE, 256, 0, stream>>>(dst, eattr, combo, rank, E);
    scan_dinv_kernel<<<1, 1024, 0, stream>>>(combo, row_ptr, dinv, N);
    scatter2_kernel<<<gE, 256, 0, stream>>>(src, dst, eattr, rank, row_ptr, dinv, edge, E);

    cast_bf16_kernel<<<(N * F / 4 + 255) / 256, 256, 0, stream>>>(node, nodeb, N * F / 4);
    wtrans_kernel<<<(F * H + 255) / 256, 256, 0, stream>>>(W1, Wt1, F, H);
    for (int i = 0; i < L; ++i)
        wtrans_kernel<<<(H * H + 255) / 256, 256, 0, stream>>>(
            W_convs + (size_t)i * H * H, Wtc + (size_t)i * H * H, H, H);

    int agg_grid = (N + 3) / 4;
    dim3 ggrid(H / 64, (N + 63) / 64);

    // layer 1: t = agg(node) ; x1 = t @ W1 + b1   (f32 out)
    agg_node<<<agg_grid, 256, 0, stream>>>(nodeb, row_ptr, edge, dinv, tmpAgg, N);
    gemm_mfma<true><<<ggrid, 256, 0, stream>>>(tmpAgg, Wt1, bufA, b1, N, H, F);

    float* x = bufA;
    float* other = bufB;
    for (int i = 0; i < L; ++i) {
        gemm_mfma<false><<<ggrid, 256, 0, stream>>>(x, Wtc + (size_t)i * H * H, xw, nullptr, N, H, H);
        aggregate_ln2<<<agg_grid, 256, 0, stream>>>(xw, row_ptr, edge, dinv,
                                                    b_convs + (size_t)i * H, ln_g + (size_t)i * H,
                                                    ln_b + (size_t)i * H, x, other, N);
        float* t = x; x = other; other = t;
    }

    colsum_kernel<<<256, 256, 0, stream>>>(x, colsums, N);
    final_kernel<<<1, 64, 0, stream>>>(colsums, fc_W, fc_b, out, 1.0f / (float)N);
}

// Round 5
// 836.856 us; speedup vs baseline: 2.0369x; 1.0833x over previous
//
#include <hip/hip_runtime.h>

#define EPS 1e-5f
#define FIXSCALE 8388608.0f   // 2^23 fixed-point for degree accumulation

typedef __attribute__((ext_vector_type(8))) short short8;
typedef __attribute__((ext_vector_type(4))) short short4v;
typedef __attribute__((ext_vector_type(4))) float float4v;
typedef __attribute__((ext_vector_type(8))) unsigned short ushort8;

__device__ __forceinline__ unsigned short f2b(float f) {
    union { float f; unsigned u; } v; v.f = f;
    unsigned r = v.u + 0x7FFF + ((v.u >> 16) & 1);   // RNE
    return (unsigned short)(r >> 16);
}
__device__ __forceinline__ float b2f(unsigned short u) {
    union { unsigned u; float f; } v; v.u = ((unsigned)u) << 16;
    return v.f;
}

// ---------------- setup kernels ----------------

__global__ __launch_bounds__(256) void cast_bf16_kernel(const float* __restrict__ in,
                                                        unsigned short* __restrict__ out,
                                                        int n4) {
    int i = blockIdx.x * 256 + threadIdx.x;
    if (i < n4) {
        float4 v = *(const float4*)&in[i * 4];
        short4v s = (short4v){(short)f2b(v.x), (short)f2b(v.y), (short)f2b(v.z), (short)f2b(v.w)};
        *(short4v*)&out[i * 4] = s;
    }
}

// ONE atomic per edge: combo[d] += (1<<32) | fix(w); old>>32 = edge's rank in row d
__global__ __launch_bounds__(256) void rank_kernel(const int* __restrict__ dst,
                                                   const float* __restrict__ w,
                                                   unsigned long long* __restrict__ combo,
                                                   int* __restrict__ rank, int E) {
    int e = blockIdx.x * 256 + threadIdx.x;
    if (e < E) {
        int d = dst[e];
        unsigned long long pack = (1ULL << 32) | (unsigned long long)(unsigned)(w[e] * FIXSCALE);
        unsigned long long old = atomicAdd(&combo[d], pack);
        rank[e] = (int)(old >> 32);
    }
}

__global__ __launch_bounds__(1024) void scan_dinv_kernel(const unsigned long long* __restrict__ combo,
                                                         int* __restrict__ row_ptr,
                                                         float* __restrict__ dinv, int n) {
    int tid = threadIdx.x, lane = tid & 63, w = tid >> 6;
    __shared__ int wsum[16];
    __shared__ int s_carry;
    if (tid == 0) s_carry = 0;
    __syncthreads();
    for (int base = 0; base < n; base += 1024) {
        int i = base + tid;
        int v = 0;
        if (i < n) {
            unsigned long long cb = combo[i];
            v = (int)(cb >> 32);
            float degv = (float)(unsigned)(cb & 0xffffffffULL) * (1.0f / FIXSCALE);
            dinv[i] = rsqrtf(degv + 1.0f);
        }
        int x = v;
        for (int off = 1; off < 64; off <<= 1) {
            int t = __shfl_up(x, off);
            if (lane >= off) x += t;
        }
        if (lane == 63) wsum[w] = x;
        __syncthreads();
        if (w == 0 && lane < 16) {
            int s = wsum[lane];
            for (int off = 1; off < 16; off <<= 1) {
                int t = __shfl_up(s, off, 16);
                if (lane >= off) s += t;
            }
            wsum[lane] = s;
        }
        __syncthreads();
        int carry = s_carry;
        int woff = (w > 0) ? wsum[w - 1] : 0;
        if (i < n) row_ptr[i + 1] = carry + woff + x;
        __syncthreads();
        if (tid == 0) s_carry = carry + wsum[15];
        __syncthreads();
    }
    if (tid == 0) row_ptr[0] = 0;
}

__global__ __launch_bounds__(256) void scatter2_kernel(
    const int* __restrict__ src, const int* __restrict__ dst,
    const float* __restrict__ w, const int* __restrict__ rank,
    const int* __restrict__ row_ptr, const float* __restrict__ dinv,
    int2* __restrict__ edge, int E) {
    int e = blockIdx.x * 256 + threadIdx.x;
    if (e < E) {
        int d = dst[e], s = src[e];
        float wn = dinv[s] * w[e] * dinv[d];
        edge[row_ptr[d] + rank[e]] = make_int2(s, __float_as_int(wn));
    }
}

__global__ __launch_bounds__(256) void wtrans_kernel(const float* __restrict__ W,
                                                     unsigned short* __restrict__ Wt,
                                                     int K, int Nc) {
    int o = blockIdx.x * 256 + threadIdx.x;
    if (o < K * Nc) {
        int n = o / K, k = o - n * K;
        Wt[o] = f2b(W[(size_t)k * Nc + n]);
    }
}

// ---------------- bf16 MFMA GEMM, full-N strip: C[M,256] = A[M,K](f32) @ Bt[256,K]^T ----
// block = 256 thr (4 waves); tile 64 rows x 256 cols; BK=64.
// LDS stride 88 shorts: 16B-aligned, b128 frag reads <=2-way bank alias (free).
// wave w: rows [16w,16w+16); 16 col-tiles of 16; acc = 16 x float4.

#define GST 88

template <bool F32OUT>
__global__ __launch_bounds__(256) void gemm_n256(const float* __restrict__ A,
                                                 const unsigned short* __restrict__ Bt,
                                                 void* __restrict__ Cout,
                                                 const float* __restrict__ bias,
                                                 int M, int K) {
    __shared__ __align__(16) short As[64 * GST];
    __shared__ __align__(16) short Bs[256 * GST];
    int t = threadIdx.x;
    int lane = t & 63, w = t >> 6;
    int quad = lane >> 4, l16 = lane & 15;
    int row0 = blockIdx.x * 64;

    float4v acc[16];
#pragma unroll
    for (int c = 0; c < 16; ++c) acc[c] = (float4v){0.f, 0.f, 0.f, 0.f};

    int arow = t >> 2, akq = (t & 3) * 16;        // A: row, k-offset (4 x float4)
    int bcol0 = t >> 2, bko = (t & 3) * 16;       // B: col base, k-offset (2 x uint4 per col)

    for (int k_outer = 0; k_outer < K; k_outer += 64) {
        // stage A: 64 rows x 64 k, f32 -> bf16
        bool rowok = (row0 + arow) < M;
        const float* ap = &A[(size_t)(row0 + arow) * K + k_outer + akq];
#pragma unroll
        for (int j = 0; j < 4; ++j) {
            short4v sv;
            if (rowok) {
                float4 av = *(const float4*)&ap[j * 4];
                sv = (short4v){(short)f2b(av.x), (short)f2b(av.y), (short)f2b(av.z), (short)f2b(av.w)};
            } else {
                sv = (short4v){0, 0, 0, 0};
            }
            *(short4v*)&As[arow * GST + akq + j * 4] = sv;
        }
        // stage B: 256 cols x 64 k bf16
#pragma unroll
        for (int cb = 0; cb < 4; ++cb) {
            int col = bcol0 + 64 * cb;
            const unsigned short* bp = &Bt[(size_t)col * K + k_outer + bko];
#pragma unroll
            for (int u = 0; u < 2; ++u)
                *(uint4*)&Bs[col * GST + bko + u * 8] = *(const uint4*)&bp[u * 8];
        }
        __syncthreads();
#pragma unroll
        for (int k0 = 0; k0 < 64; k0 += 32) {
            short8 a = *(const short8*)&As[(w * 16 + l16) * GST + k0 + quad * 8];
#pragma unroll
            for (int c = 0; c < 16; ++c) {
                short8 b = *(const short8*)&Bs[(c * 16 + l16) * GST + k0 + quad * 8];
                acc[c] = __builtin_amdgcn_mfma_f32_16x16x32_bf16(a, b, acc[c], 0, 0, 0);
            }
        }
        __syncthreads();
    }
#pragma unroll
    for (int c = 0; c < 16; ++c) {
        int col = c * 16 + l16;
        float bcol = F32OUT ? bias[col] : 0.0f;
#pragma unroll
        for (int r = 0; r < 4; ++r) {
            int row = row0 + w * 16 + quad * 4 + r;
            if (row < M) {
                if (F32OUT)
                    ((float*)Cout)[(size_t)row * 256 + col] = acc[c][r] + bcol;
                else
                    ((unsigned short*)Cout)[(size_t)row * 256 + col] = f2b(acc[c][r]);
            }
        }
    }
}

// ---------------- layer-1 aggregation on raw node features (F=128, 256B bf16 rows) ----
// one wave per node; quarter q covers one edge's row (16 lanes x 16B); 2 iter-groups in flight

__global__ __launch_bounds__(256) void agg_node(
    const unsigned short* __restrict__ nodeb, const int* __restrict__ row_ptr,
    const int2* __restrict__ edge, const float* __restrict__ dinv,
    float* __restrict__ out, int n) {
    int wv = __builtin_amdgcn_readfirstlane(threadIdx.x >> 6);
    int d = blockIdx.x * 4 + wv;
    if (d >= n) return;
    int l = threadIdx.x & 63;
    int q = l >> 4, sl = l & 15;
    int j0 = row_ptr[d];
    int cnt = row_ptr[d + 1] - j0;
    float di = dinv[d];
    float selfw = di * di;

    float a[8] = {0.f, 0.f, 0.f, 0.f, 0.f, 0.f, 0.f, 0.f};
    {   // peel: q=0 -> self, q=1..3 -> edges 0..2
        bool ev = (q >= 1) && (q - 1 < cnt);
        int2 e = edge[j0 + (ev ? q - 1 : 0)];
        int s = (q == 0) ? d : (ev ? e.x : d);
        float wgt = (q == 0) ? selfw : (ev ? __int_as_float(e.y) : 0.0f);
        ushort8 r = *(const ushort8*)&nodeb[((size_t)s << 7) + (sl << 3)];
#pragma unroll
        for (int k = 0; k < 8; ++k) a[k] += b2f(r[k]) * wgt;
    }
    for (int t = 3; t < cnt; t += 8) {
        int ss[2]; float ww[2];
#pragma unroll
        for (int u = 0; u < 2; ++u) {
            int m = t + 4 * u + q;
            bool v = m < cnt;
            int2 e = edge[j0 + (v ? m : 0)];
            ss[u] = v ? e.x : d;
            ww[u] = v ? __int_as_float(e.y) : 0.0f;
        }
        ushort8 r0 = *(const ushort8*)&nodeb[((size_t)ss[0] << 7) + (sl << 3)];
        ushort8 r1 = *(const ushort8*)&nodeb[((size_t)ss[1] << 7) + (sl << 3)];
#pragma unroll
        for (int k = 0; k < 8; ++k) a[k] += b2f(r0[k]) * ww[0];
#pragma unroll
        for (int k = 0; k < 8; ++k) a[k] += b2f(r1[k]) * ww[1];
    }
#pragma unroll
    for (int k = 0; k < 8; ++k) {
        a[k] += __shfl_xor(a[k], 16);
        a[k] += __shfl_xor(a[k], 32);
    }
    if (q < 2) {
        float4 o = (q == 0) ? make_float4(a[0], a[1], a[2], a[3])
                            : make_float4(a[4], a[5], a[6], a[7]);
        *(float4*)&out[(size_t)d * 128 + (sl << 3) + q * 4] = o;
    }
}

// ---------------- conv aggregation + bias + LN + residual + ReLU ----------------
// one wave per node; half h covers one edge's 512B row (32 lanes x 16B); 4 gathers in flight

__global__ __launch_bounds__(256) void aggregate_ln2(
    const unsigned short* __restrict__ xw, const int* __restrict__ row_ptr,
    const int2* __restrict__ edge, const float* __restrict__ dinv,
    const float* __restrict__ bias, const float* __restrict__ g,
    const float* __restrict__ lb, const float* __restrict__ res,
    float* __restrict__ out, int n) {
    int wv = __builtin_amdgcn_readfirstlane(threadIdx.x >> 6);
    int d = blockIdx.x * 4 + wv;
    if (d >= n) return;
    int l = threadIdx.x & 63;
    int h = l >> 5, sl = l & 31;
    int j0 = row_ptr[d];
    int cnt = row_ptr[d + 1] - j0;
    float di = dinv[d];
    float selfw = di * di;

    float a[8] = {0.f, 0.f, 0.f, 0.f, 0.f, 0.f, 0.f, 0.f};
    {   // peel: h=0 -> self, h=1 -> edge 0
        bool ev = (h == 1) && (cnt > 0);
        int2 e = edge[j0];
        int s = (h == 0) ? d : (ev ? e.x : d);
        float wgt = (h == 0) ? selfw : (ev ? __int_as_float(e.y) : 0.0f);
        ushort8 r = *(const ushort8*)&xw[((size_t)s << 8) + (sl << 3)];
#pragma unroll
        for (int k = 0; k < 8; ++k) a[k] += b2f(r[k]) * wgt;
    }
    for (int t = 1; t < cnt; t += 8) {
        int ss[4]; float ww[4];
#pragma unroll
        for (int u = 0; u < 4; ++u) {
            int m = t + 2 * u + h;
            bool v = m < cnt;
            int2 e = edge[j0 + (v ? m : 0)];
            ss[u] = v ? e.x : d;
            ww[u] = v ? __int_as_float(e.y) : 0.0f;
        }
        ushort8 r[4];
#pragma unroll
        for (int u = 0; u < 4; ++u)
            r[u] = *(const ushort8*)&xw[((size_t)ss[u] << 8) + (sl << 3)];
#pragma unroll
        for (int u = 0; u < 4; ++u)
#pragma unroll
            for (int k = 0; k < 8; ++k) a[k] += b2f(r[u][k]) * ww[u];
    }
    // cross-half combine: lane ends with v[j] = total[4h+j], features f = 8*sl + 4*h + j
    int fo = (sl << 3) + (h << 2);
    float4 bb = *(const float4*)&bias[fo];
    float bbv[4] = {bb.x, bb.y, bb.z, bb.w};
    float v[4];
#pragma unroll
    for (int j = 0; j < 4; ++j) {
        float send = h ? a[j] : a[4 + j];
        float keep = h ? a[4 + j] : a[j];
        v[j] = keep + __shfl_xor(send, 32) + bbv[j];
    }
    float s4 = v[0] + v[1] + v[2] + v[3];
#pragma unroll
    for (int off = 1; off < 64; off <<= 1) s4 += __shfl_xor(s4, off);
    float mu = s4 * (1.0f / 256.0f);
    float dv[4];
    float qs = 0.f;
#pragma unroll
    for (int j = 0; j < 4; ++j) { dv[j] = v[j] - mu; qs += dv[j] * dv[j]; }
#pragma unroll
    for (int off = 1; off < 64; off <<= 1) qs += __shfl_xor(qs, off);
    float rs = rsqrtf(qs * (1.0f / 256.0f) + EPS);

    float4 gg = *(const float4*)&g[fo];
    float4 lbv = *(const float4*)&lb[fo];
    float4 rr = *(const float4*)&res[(size_t)d * 256 + fo];
    float ggv[4] = {gg.x, gg.y, gg.z, gg.w};
    float lbvv[4] = {lbv.x, lbv.y, lbv.z, lbv.w};
    float rrv[4] = {rr.x, rr.y, rr.z, rr.w};
    float o[4];
#pragma unroll
    for (int j = 0; j < 4; ++j) {
        float x = dv[j] * rs * ggv[j] + lbvv[j] + rrv[j];
        o[j] = x > 0.f ? x : 0.f;
    }
    *(float4*)&out[(size_t)d * 256 + fo] = make_float4(o[0], o[1], o[2], o[3]);
}

// ---------------- head ----------------

__global__ __launch_bounds__(256) void colsum_kernel(const float* __restrict__ x,
                                                     float* __restrict__ sums, int n) {
    int h = threadIdx.x;
    float acc = 0.0f;
    for (int r = blockIdx.x; r < n; r += gridDim.x) acc += x[(size_t)r * 256 + h];
    atomicAdd(&sums[h], acc);
}

__global__ __launch_bounds__(64) void final_kernel(const float* __restrict__ sums,
                                                   const float* __restrict__ fcW,
                                                   const float* __restrict__ fcb,
                                                   float* __restrict__ out, float invN) {
    int lane = threadIdx.x;
    float p0 = 0.0f, p1 = 0.0f;
    for (int hh = lane; hh < 256; hh += 64) {
        float m = sums[hh];
        p0 += m * fcW[hh * 2 + 0];
        p1 += m * fcW[hh * 2 + 1];
    }
    for (int off = 32; off > 0; off >>= 1) {
        p0 += __shfl_down(p0, off);
        p1 += __shfl_down(p1, off);
    }
    if (lane == 0) {
        out[0] = p0 * invN + fcb[0];
        out[1] = p1 * invN + fcb[1];
    }
}

// ---------------- launch ----------------

extern "C" void kernel_launch(void* const* d_in, const int* in_sizes, int n_in,
                              void* d_out, int out_size, void* d_ws, size_t ws_size,
                              hipStream_t stream) {
    const float* node    = (const float*)d_in[0];
    const int*   edges   = (const int*)d_in[1];
    const float* eattr   = (const float*)d_in[2];
    const float* W1      = (const float*)d_in[3];
    const float* b1      = (const float*)d_in[4];
    const float* W_convs = (const float*)d_in[5];
    const float* b_convs = (const float*)d_in[6];
    const float* ln_g    = (const float*)d_in[7];
    const float* ln_b    = (const float*)d_in[8];
    const float* fc_W    = (const float*)d_in[9];
    const float* fc_b    = (const float*)d_in[10];
    float* out = (float*)d_out;

    const int H = in_sizes[4];           // 256
    const int F = in_sizes[3] / H;       // 128
    const int N = in_sizes[0] / F;       // 50000
    const int E = in_sizes[2];           // 1600000
    const int L = in_sizes[6] / H;       // 3

    const int* src = edges;
    const int* dst = edges + E;

    char* p = (char*)d_ws;
    auto alloc = [&](size_t bytes) {
        char* r = p;
        p += (bytes + 255) & ~(size_t)255;
        return r;
    };
    unsigned long long* combo = (unsigned long long*)alloc((size_t)N * 8);
    float* colsums = (float*)alloc((size_t)H * 4);
    size_t zero_bytes = (size_t)((char*)colsums - (char*)combo) + (((size_t)H * 4 + 255) & ~(size_t)255);
    float* dinv    = (float*)alloc((size_t)N * 4);
    int*   row_ptr = (int*)alloc((size_t)(N + 1) * 4);
    int2*  edge    = (int2*)alloc((size_t)(E + 8) * 8);
    unsigned short* Wt1 = (unsigned short*)alloc((size_t)H * F * 2);
    unsigned short* Wtc = (unsigned short*)alloc((size_t)L * H * H * 2);
    unsigned short* xw  = (unsigned short*)alloc((size_t)N * H * 2);
    float* bufA    = (float*)alloc((size_t)N * H * 4);
    float* bufB    = (float*)alloc((size_t)N * H * 4);
    // transient slabs aliased into bufB (dead before bufB's first real write):
    int*            rank   = (int*)bufB;                                              // E*4
    unsigned short* nodeb  = (unsigned short*)((char*)bufB + (((size_t)E * 4 + 255) & ~(size_t)255));
    float*          tmpAgg = (float*)((char*)nodeb + (((size_t)N * F * 2 + 255) & ~(size_t)255));

    hipMemsetAsync(combo, 0, zero_bytes, stream);

    int gE = (E + 255) / 256;
    rank_kernel<<<gE, 256, 0, stream>>>(dst, eattr, combo, rank, E);
    scan_dinv_kernel<<<1, 1024, 0, stream>>>(combo, row_ptr, dinv, N);
    scatter2_kernel<<<gE, 256, 0, stream>>>(src, dst, eattr, rank, row_ptr, dinv, edge, E);

    cast_bf16_kernel<<<(N * F / 4 + 255) / 256, 256, 0, stream>>>(node, nodeb, N * F / 4);
    wtrans_kernel<<<(F * H + 255) / 256, 256, 0, stream>>>(W1, Wt1, F, H);
    for (int i = 0; i < L; ++i)
        wtrans_kernel<<<(H * H + 255) / 256, 256, 0, stream>>>(
            W_convs + (size_t)i * H * H, Wtc + (size_t)i * H * H, H, H);

    int agg_grid = (N + 3) / 4;
    int ggrid = (N + 63) / 64;

    // layer 1: t = agg(node) ; x1 = t @ W1 + b1   (f32 out)
    agg_node<<<agg_grid, 256, 0, stream>>>(nodeb, row_ptr, edge, dinv, tmpAgg, N);
    gemm_n256<true><<<ggrid, 256, 0, stream>>>(tmpAgg, Wt1, bufA, b1, N, F);

    float* x = bufA;
    float* other = bufB;
    for (int i = 0; i < L; ++i) {
        gemm_n256<false><<<ggrid, 256, 0, stream>>>(x, Wtc + (size_t)i * H * H, xw, nullptr, N, H);
        aggregate_ln2<<<agg_grid, 256, 0, stream>>>(xw, row_ptr, edge, dinv,
                                                    b_convs + (size_t)i * H, ln_g + (size_t)i * H,
                                                    ln_b + (size_t)i * H, x, other, N);
        float* t = x; x = other; other = t;
    }

    colsum_kernel<<<256, 256, 0, stream>>>(x, colsums, N);
    final_kernel<<<1, 64, 0, stream>>>(colsums, fc_W, fc_b, out, 1.0f / (float)N);
}